// Round 10
// baseline (309.141 us; speedup 1.0000x reference)
//
#include <hip/hip_runtime.h>

#define HP   768      // padded H (=W)
#define NV   385      // HP/2 + 1
#define HIN  512
#define WIN  512
#define K    8        // truncation radius of spatial inverse kernel
#define A    17       // 2K+1
#define PADO 136      // PAD + K = 128 + 8
#define TW   64       // output tile width
#define TH   64       // output tile height
#define LH   80       // TH + 2K staged rows
#define LWL  80       // TW + 2K (logical tile width)
#define LWS  84       // LDS row stride (84 words: ty*84 %32 spreads 8 bank offsets)
#define SUBROWS 20    // rows per 4-way parity sub-array (80/4)
#define SUBSIZE (SUBROWS * LWS)   // 1680 floats

#define OB   120      // active-region origin: nonzero out rows/cols = [120, 648)
#define OE   648      // active-region end (exclusive)
#define NT9  9        // 9x9 tiles cover [120, 696) >= [120, 648)
#define ACT0_Q 30     // 120/4  (float4 index of active col start)
#define ACT1_Q 174    // 696/4  (float4 index of active col end)

#define TWO_PI_OVER_HP 0.008181230868723419f  // 2*pi/768

typedef float f4v __attribute__((ext_vector_type(4)));

__device__ inline float2 cmul(float2 a, float2 b) {
    return make_float2(a.x*b.x - a.y*b.y, a.x*b.y + a.y*b.x);
}

// F(u,v) = sum_{i<3,j<3} w[i,j] * exp(-2*pi*i*(u*i + v*j)/768), via LDS table
__device__ inline float2 evalF_t(int u, int v, const float* w9,
                                 const float2* __restrict__ tbl) {
    float fr = 0.f, fi = 0.f;
#pragma unroll
    for (int i = 0; i < 3; ++i) {
#pragma unroll
        for (int j = 0; j < 3; ++j) {
            int idx = u * i + v * j;          // <= 2302
            if (idx >= 2 * HP) idx -= 2 * HP;
            if (idx >= HP)     idx -= HP;
            float2 e = tbl[idx];
            float wv = w9[i * 3 + j];
            fr += wv * e.x;
            fi -= wv * e.y;
        }
    }
    return make_float2(fr, fi);
}

// One block per rfft column v. Builds gmf[.,v] in LDS, then
// P[a,v] = sum_u gmf[u,v] * exp(+2*pi*i*u*(a-K)/768)  for all 17 taps,
// parallelized 16 threads per tap.
__global__ __launch_bounds__(320) void filt_P_kernel(
        const float* __restrict__ w, float2* __restrict__ P) {
    __shared__ float2 tbl[HP];
    __shared__ float2 lg[HP];
    __shared__ float2 red[20][16];
    int v = blockIdx.x;
    int tid = threadIdx.x;

    float w9[9];
#pragma unroll
    for (int i = 0; i < 9; ++i) w9[i] = w[i];

    for (int m = tid; m < HP; m += 320) {
        float s, c;
        sincosf((float)m * TWO_PI_OVER_HP, &s, &c);
        tbl[m] = make_float2(c, s);
    }
    __syncthreads();

    int sv = (v == 0) ? 0 : (NV - v);   // reference's reverse+roll index
    for (int u = tid; u < HP; u += 320) {
        int su = (HP - u) % HP;
        float2 F1 = evalF_t(u,  v,  w9, tbl);
        float2 F2 = evalF_t(su, v,  w9, tbl);
        float2 F3 = evalF_t(u,  sv, w9, tbl);
        float2 F4 = evalF_t(su, sv, w9, tbl);
        float2 pr = cmul(cmul(F1, F2), cmul(F3, F4));
        float d = pr.x * pr.x + pr.y * pr.y;
        lg[u] = make_float2(pr.x / d, -pr.y / d);   // 1/prod
    }
    __syncthreads();

    int a   = tid >> 4;   // 0..19 (taps 0..16 valid)
    int sub = tid & 15;
    if (a < A) {
        int ap  = a - K;
        int apu = (ap < 0) ? ap + HP : ap;
        float Pr = 0.f, Pi = 0.f;
        for (int u = sub; u < HP; u += 16) {
            int idx = (u * apu) % HP;
            float2 e = tbl[idx];
            float2 g = lg[u];
            Pr += g.x * e.x - g.y * e.y;
            Pi += g.x * e.y + g.y * e.x;
        }
        red[a][sub] = make_float2(Pr, Pi);
    }
    __syncthreads();
    if (tid < A) {
        float Pr = 0.f, Pi = 0.f;
#pragma unroll
        for (int s2 = 0; s2 < 16; ++s2) { Pr += red[tid][s2].x; Pi += red[tid][s2].y; }
        P[tid * NV + v] = make_float2(Pr, Pi);
    }
}

// g[a,b] = (1/768^2) * sum_v w_v * Re(P[a,v] * exp(+2*pi*i*v*(b-K)/768))
// Stored FLIPPED: gkf[(16-a)*17 + (16-b)] = g[a,b], so deconv reads ascending.
__global__ __launch_bounds__(320) void filt_gk_kernel(
        const float2* __restrict__ P, float* __restrict__ gkf) {
    __shared__ float2 tbl[HP];      // 6144 B
    __shared__ float2 Prow[NV];     // 3080 B
    __shared__ float  red[20][16];  // 1280 B
    int ai  = blockIdx.x;           // 0..16
    int tid = threadIdx.x;

    for (int m = tid; m < HP; m += 320) {
        float s, c;
        sincosf((float)m * TWO_PI_OVER_HP, &s, &c);
        tbl[m] = make_float2(c, s);
    }
    for (int m = tid; m < NV; m += 320)
        Prow[m] = P[ai * NV + m];
    __syncthreads();

    int bi  = tid >> 4;   // 0..19 (taps 0..16 valid)
    int sub = tid & 15;
    if (bi < A) {
        int bp  = bi - K;
        int bpu = (bp < 0) ? bp + HP : bp;
        float sum = 0.f;
        for (int vv = sub; vv < NV; vv += 16) {
            float wv = (vv == 0 || vv == NV - 1) ? 1.f : 2.f;
            int idx = (vv * bpu) % HP;
            float2 e = tbl[idx];
            float2 p = Prow[vv];
            sum += wv * (p.x * e.x - p.y * e.y);
        }
        red[bi][sub] = sum;
    }
    __syncthreads();
    if (tid < A) {
        float s = 0.f;
#pragma unroll
        for (int s2 = 0; s2 < 16; ++s2) s += red[tid][s2];
        gkf[(2 * K - ai) * A + (2 * K - tid)] = s * (1.f / ((float)HP * (float)HP));
    }
}

// Zero everything outside the deconv-covered square [OB, OB+9*64) x [OB, OB+9*64).
__global__ __launch_bounds__(256) void zero_border_kernel(float* __restrict__ out) {
    int gid  = blockIdx.x;            // 64 imgs * 192 row-groups
    int img  = gid / 192;
    int rg   = gid - img * 192;
    int lane = threadIdx.x & 63;
    int w    = threadIdx.x >> 6;      // wave 0..3 -> one row each
    int row  = rg * 4 + w;
    f4v* base = (f4v*)(out + ((size_t)img * HP + row) * HP);
    f4v z = {0.f, 0.f, 0.f, 0.f};
    if (row >= OB && row < OB + NT9 * TH) {
        // side strips: cols [0,120) and [696,768)
        if (lane < ACT0_Q)
            __builtin_nontemporal_store(z, base + lane);
        else if (lane < ACT0_Q + (192 - ACT1_Q))
            __builtin_nontemporal_store(z, base + ACT1_Q + (lane - ACT0_Q));
    } else {
        // full row: 192 float4 = 64 lanes x 3
        __builtin_nontemporal_store(z, base + lane);
        __builtin_nontemporal_store(z, base + lane + 64);
        __builtin_nontemporal_store(z, base + lane + 128);
    }
}

// Direct 17x17 convolution, 9x9 active tiles (origin OB=120).
// R=4 restructure: block (8,16) = 2 waves; thread computes 8 cols x 4 rows.
// Each 24-float row window now feeds up to 4 tap-rows (544 FMAs) -> ~1100-cyc
// compute shadow per 6 ds_read_b128, hiding LDS latency by ILP instead of
// relying on the register allocator keeping two buffers live (it wouldn't:
// VGPR_Count=44 in the R=2 version, rematerializing LDS reads per cluster).
// LDS: 4-way row-parity [4][20][84] (26880 B, same as before); ty-stride 84
// words -> 8 distinct bank offsets (2-way aliasing = free, m136).
// Per-acc tap order unchanged (a ascending) -> bit-identical output.
__global__ __launch_bounds__(128, 3) void deconv_kernel(
        const float* __restrict__ x, const float* __restrict__ gkf,
        float* __restrict__ out) {
    __shared__ __align__(16) float tile[4 * SUBSIZE];   // 26880 B

    const int tx = threadIdx.x;   // 0..7
    const int ty = threadIdx.y;   // 0..15
    const int tid = ty * 8 + tx;
    const int bx = blockIdx.x, by = blockIdx.y, bz = blockIdx.z;

    const int ix0 = bx * TW + (OB - PADO);   // = 64*bx - 16  (% 4 == 0)
    const int iy0 = by * TH + (OB - PADO);
    const int oy0 = OB + by * TH + ty * 4;
    const int ox0 = OB + bx * TW + tx * 8;
    float* orow = out + ((size_t)bz * HP + oy0) * HP + ox0;

    // stage input tile (float4-granular; ix0 % 4 == 0 so no partial float4)
    const float* xb = x + (size_t)bz * (HIN * WIN);
    for (int l = tid; l < LH * (LWL / 4); l += 128) {   // 80*20 = 1600
        int r = l / 20, c4 = l - r * 20;
        int gy = iy0 + r;
        int gx = ix0 + c4 * 4;
        f4v val = {0.f, 0.f, 0.f, 0.f};
        if ((unsigned)gy < (unsigned)HIN && (unsigned)gx < (unsigned)WIN)
            val = *(const f4v*)&xb[gy * WIN + gx];
        *(f4v*)&tile[(r & 3) * SUBSIZE + (r >> 2) * LWS + c4 * 4] = val;
    }
    __syncthreads();

    // Early-out: output rows >= OE are provably zero (input support ends at
    // padded row 640, taps reach +8 => out < 648). by==8: wave1 (ty>=8)
    // retires whole; wave0 lanes ty=4..7 mask off here too.
    if (oy0 >= OE) {
        f4v z = {0.f, 0.f, 0.f, 0.f};
#pragma unroll
        for (int j = 0; j < 4; ++j) {
            __builtin_nontemporal_store(z, (f4v*)(orow + j * HP));
            __builtin_nontemporal_store(z, (f4v*)(orow + j * HP) + 1);
        }
        return;
    }

    float acc0[8], acc1[8], acc2[8], acc3[8];
#pragma unroll
    for (int c = 0; c < 8; ++c) { acc0[c] = 0.f; acc1[c] = 0.f; acc2[c] = 0.f; acc3[c] = 0.f; }

    // two 24-float row windows (6 x f4v each)
    f4v rbX[6], rbY[6];
    const float* tlane = tile + ty * LWS + tx * 8;   // per-lane base

    // rel input row = 4*ty + p; sub = p&3 (wave-uniform), idx = ty + (p>>2)
    auto loadRow = [&](f4v* rb, int p) {
        const float* ptr = tlane + (p & 3) * SUBSIZE + (p >> 2) * LWS;
#pragma unroll
        for (int q = 0; q < 6; ++q)
            rb[q] = *(const f4v*)&ptr[q * 4];
    };
    // one tap-row (17 coeffs) into one 8-wide accumulator; static rb indices
    auto fmaRow = [&](int a, const f4v* r, float* acc) {
        const float* gp = gkf + a * A;
#pragma unroll
        for (int bb = 0; bb < A; ++bb) {
            float g = gp[bb];
#pragma unroll
            for (int c = 0; c < 8; ++c) {
                int i = bb + c;
                acc[c] += g * r[i >> 2][i & 3];
            }
        }
    };

    // prologue: p = 0,1,2
    loadRow(rbX, 0);
    loadRow(rbY, 1);
    fmaRow(0, rbX, acc0);                    // p=0: j=0
    loadRow(rbX, 2);
    fmaRow(1, rbY, acc0);                    // p=1: j=0
    fmaRow(0, rbY, acc1);                    //      j=1
    loadRow(rbY, 3);
    fmaRow(2, rbX, acc0);                    // p=2: j=0
    fmaRow(1, rbX, acc1);
    fmaRow(0, rbX, acc2);

    // steady: p = 3..16 (all 4 rows), two p per iteration, double-buffered
#pragma unroll 1
    for (int pp = 3; pp <= 15; pp += 2) {
        loadRow(rbX, pp + 1);                // in flight under 544 FMAs on Y
        fmaRow(pp,     rbY, acc0);           // p = pp (odd)
        fmaRow(pp - 1, rbY, acc1);
        fmaRow(pp - 2, rbY, acc2);
        fmaRow(pp - 3, rbY, acc3);
        loadRow(rbY, pp + 2);                // in flight under 544 FMAs on X
        fmaRow(pp + 1, rbX, acc0);           // p = pp+1 (even)
        fmaRow(pp,     rbX, acc1);
        fmaRow(pp - 1, rbX, acc2);
        fmaRow(pp - 2, rbX, acc3);
    }

    // epilogue: p = 17,18,19 (rbY holds p=17 from the last iteration)
    fmaRow(16, rbY, acc1);                   // p=17: j=1..3
    fmaRow(15, rbY, acc2);
    fmaRow(14, rbY, acc3);
    loadRow(rbX, 18);
    fmaRow(16, rbX, acc2);                   // p=18: j=2,3
    fmaRow(15, rbX, acc3);
    loadRow(rbY, 19);
    fmaRow(16, rbY, acc3);                   // p=19: j=3

    auto st = [&](const float* acc, float* row) {
        f4v v0 = {acc[0], acc[1], acc[2], acc[3]};
        f4v v1 = {acc[4], acc[5], acc[6], acc[7]};
        __builtin_nontemporal_store(v0, (f4v*)row);
        __builtin_nontemporal_store(v1, (f4v*)row + 1);
    };
    st(acc0, orow);
    st(acc1, orow + HP);
    st(acc2, orow + 2 * HP);
    st(acc3, orow + 3 * HP);
}

extern "C" void kernel_launch(void* const* d_in, const int* in_sizes, int n_in,
                              void* d_out, int out_size, void* d_ws, size_t ws_size,
                              hipStream_t stream) {
    const float* x = (const float*)d_in[0];   // (64, 512, 512) fp32
    const float* w = (const float*)d_in[1];   // (3, 3) fp32
    float* out = (float*)d_out;               // (64, 768, 768) fp32

    // workspace layout (floats): P = A*NV float2, then gkf = A*A floats
    float2* P   = (float2*)d_ws;
    float*  gkf = (float*)d_ws + (size_t)A * NV * 2;

    filt_P_kernel<<<dim3(NV), dim3(320), 0, stream>>>(w, P);
    filt_gk_kernel<<<dim3(A), dim3(320), 0, stream>>>(P, gkf);
    zero_border_kernel<<<dim3(64 * 192), dim3(256), 0, stream>>>(out);
    deconv_kernel<<<dim3(NT9, NT9, 64), dim3(8, 16), 0, stream>>>(x, gkf, out);
}